// Round 5
// baseline (513.151 us; speedup 1.0000x reference)
//
#include <hip/hip_runtime.h>
#include <cstdint>

#define SEQ 2048
#define BATCH 2
#define NTOK 4096      // B*S
#define HID 2048
#define NH 32
#define NKV 4
#define HD 128
#define QKV_O 5120     // (32+8)*128

typedef __attribute__((ext_vector_type(8))) short short8;
typedef __attribute__((ext_vector_type(8))) unsigned short u16x8;
typedef __attribute__((ext_vector_type(4))) unsigned short u16x4;
typedef __attribute__((ext_vector_type(4))) float f32x4;

__device__ __forceinline__ float bf2f(unsigned short u) {
  union { unsigned int i; float f; } v; v.i = ((unsigned int)u) << 16; return v.f;
}
__device__ __forceinline__ unsigned short f2bf(float f) {
  union { float f; unsigned int i; } v; v.f = f;
  unsigned int r = v.i + 0x7FFFu + ((v.i >> 16) & 1u);
  return (unsigned short)(r >> 16);
}

// async global->LDS, 16 B per lane. LDS dest is wave-uniform base + lane*16.
__device__ __forceinline__ void load_lds16(const void* g, void* l) {
  __builtin_amdgcn_global_load_lds((const __attribute__((address_space(1))) unsigned int*)g,
                                   (__attribute__((address_space(3))) unsigned int*)l, 16, 0, 0);
}

// ---------------------------------------------------------------------------
// fp32 -> bf16 (round-to-nearest-even), vectorized. n4 = n/4.
// ---------------------------------------------------------------------------
__global__ __launch_bounds__(256) void convert_to_bf16(const float* __restrict__ src,
                                                       unsigned short* __restrict__ dst,
                                                       int n4) {
  int i = blockIdx.x * blockDim.x + threadIdx.x;
  int stride = gridDim.x * blockDim.x;
  for (; i < n4; i += stride) {
    f32x4 v = *(const f32x4*)(src + 4 * (size_t)i);
    u16x4 o;
    o.x = f2bf(v.x); o.y = f2bf(v.y); o.z = f2bf(v.z); o.w = f2bf(v.w);
    *(u16x4*)(dst + 4 * (size_t)i) = o;
  }
}

// ---------------------------------------------------------------------------
// out4 += part4 (fp32), grid-stride. Reduce for split-K.
// ---------------------------------------------------------------------------
__global__ __launch_bounds__(256) void reduce_add(float* __restrict__ out,
                                                  const float* __restrict__ part, int n4) {
  int i = blockIdx.x * blockDim.x + threadIdx.x;
  int stride = gridDim.x * blockDim.x;
  for (; i < n4; i += stride) {
    f32x4 a = *(const f32x4*)(out + 4 * (size_t)i);
    f32x4 b = *(const f32x4*)(part + 4 * (size_t)i);
    a.x += b.x; a.y += b.y; a.z += b.z; a.w += b.w;
    *(f32x4*)(out + 4 * (size_t)i) = a;
  }
}

// ---------------------------------------------------------------------------
// 256x256-tile GEMM, 4-deep pipelined (T3+T4): C = A[M,K] * B[N,K]^T.
// BK=32 K-steps; LDS = 4 step-buffers x (256x32) x {A,B} = 128 KiB.
// 512 thr (8 waves, 2M x 4N), per-wave output 128x64, 32 MFMA/step.
// Staging via global_load_lds(16B): 4 loads/thread/step (2 A + 2 B),
// linear LDS dest + inverse-XOR-swizzled source (chunk ^= row&3) +
// swizzled reads -> conflict-free (R3-measured: SQ_LDS_BANK_CONFLICT=0).
// COUNTED vmcnt(8) per step (3 steps = 12 loads in flight, wait only the
// oldest 4 = the step about to be consumed) -- never vmcnt(0) in the loop.
// One raw s_barrier per step: also guards buffer reuse (stage s+3 targets
// buf (s-1)&3, last read in step s-1, done by this barrier).
// SPLIT: gridDim.z=2 halves K; z=0 -> C0 (fp32 partial), z=1 -> C1.
// ---------------------------------------------------------------------------
template <bool OUT_F32, bool SPLIT>
__global__ __launch_bounds__(512, 2) void gemm256_p4(
    const unsigned short* __restrict__ A, const unsigned short* __restrict__ B,
    void* __restrict__ C0, void* __restrict__ C1,
    int lda, int ldb, int ldc, int Kloop) {
  __shared__ alignas(16) unsigned short As[4][256 * 32];
  __shared__ alignas(16) unsigned short Bs[4][256 * 32];

  const int t = threadIdx.x;
  const int lane = t & 63, w = t >> 6;
  const int fr = lane & 15, g = lane >> 4;
  const int wm = w >> 2, wn = w & 3;                 // 2 x 4 wave grid
  const size_t m0 = (size_t)blockIdx.y * 256;
  const size_t n0 = (size_t)blockIdx.x * 256;
  const int kbase = SPLIT ? (int)blockIdx.z * Kloop : 0;
  void* Cv = (SPLIT && blockIdx.z) ? C1 : C0;

  // staging: thread t owns slots {t, t+512} of each 1024x16B step-tile.
  // slot s -> LDS row s>>2, chunk s&3; source chunk = (s&3) ^ (row&3).
  const int rA0 = t >> 2;         const int cA0 = (t & 3) ^ (rA0 & 3);
  const int rA1 = (t + 512) >> 2; const int cA1 = ((t + 512) & 3) ^ (rA1 & 3);
  const unsigned short* gA0 = A + (m0 + rA0) * (size_t)lda + kbase + cA0 * 8;
  const unsigned short* gA1 = A + (m0 + rA1) * (size_t)lda + kbase + cA1 * 8;
  const unsigned short* gB0 = B + (n0 + rA0) * (size_t)ldb + kbase + cA0 * 8;
  const unsigned short* gB1 = B + (n0 + rA1) * (size_t)ldb + kbase + cA1 * 8;

  auto stage = [&](int s) {
    const int bi = s & 3;
    const int kk = s * 32;
    load_lds16(gA0 + kk, &As[bi][(w * 64) * 8]);
    load_lds16(gA1 + kk, &As[bi][(512 + w * 64) * 8]);
    load_lds16(gB0 + kk, &Bs[bi][(w * 64) * 8]);
    load_lds16(gB1 + kk, &Bs[bi][(512 + w * 64) * 8]);
  };

  f32x4 acc[8][4] = {};
  const int NK = Kloop / 32;
  stage(0); stage(1); stage(2);                      // 12 loads in flight

  const int kc = (g ^ (fr & 3)) * 8;                 // swizzled chunk (shorts)
  const int arow = wm * 128 + fr;                    // + mf*16
  const int brow = wn * 64 + fr;                     // + nf*16

  for (int s = 0; s < NK; s++) {
    // wait ONLY for step s's 4 loads (steps s+1,s+2 stay in flight = 8)
    asm volatile("s_waitcnt vmcnt(8)" ::: "memory");
    __builtin_amdgcn_s_barrier();
    __builtin_amdgcn_sched_barrier(0);
    if (s + 3 < NK) stage(s + 3);                    // -> buf (s-1)&3, now free

    const unsigned short* Ac = As[s & 3];
    const unsigned short* Bc = Bs[s & 3];

    short8 bfr[4];
#pragma unroll
    for (int nf = 0; nf < 4; nf++)
      bfr[nf] = *(const short8*)&Bc[(brow + nf * 16) * 32 + kc];
    short8 af[4];
#pragma unroll
    for (int mf = 0; mf < 4; mf++)
      af[mf] = *(const short8*)&Ac[(arow + mf * 16) * 32 + kc];
    __builtin_amdgcn_s_setprio(1);
#pragma unroll
    for (int mf = 0; mf < 4; mf++)
#pragma unroll
      for (int nf = 0; nf < 4; nf++)
        acc[mf][nf] = __builtin_amdgcn_mfma_f32_16x16x32_bf16(af[mf], bfr[nf], acc[mf][nf], 0, 0, 0);
    __builtin_amdgcn_s_setprio(0);

    short8 af2[4];
#pragma unroll
    for (int mf = 0; mf < 4; mf++)
      af2[mf] = *(const short8*)&Ac[(arow + (mf + 4) * 16) * 32 + kc];
    __builtin_amdgcn_s_setprio(1);
#pragma unroll
    for (int mf = 0; mf < 4; mf++)
#pragma unroll
      for (int nf = 0; nf < 4; nf++)
        acc[mf + 4][nf] = __builtin_amdgcn_mfma_f32_16x16x32_bf16(af2[mf], bfr[nf], acc[mf + 4][nf], 0, 0, 0);
    __builtin_amdgcn_s_setprio(0);
  }

  // epilogue: C/D layout col=lane&15, row=(lane>>4)*4+reg
#pragma unroll
  for (int mf = 0; mf < 8; mf++)
#pragma unroll
    for (int nf = 0; nf < 4; nf++) {
      size_t row = m0 + wm * 128 + mf * 16 + g * 4;
      size_t col = n0 + wn * 64 + nf * 16 + fr;
#pragma unroll
      for (int r = 0; r < 4; r++) {
        if (OUT_F32) ((float*)Cv)[(row + r) * ldc + col] = acc[mf][nf][r];
        else ((unsigned short*)Cv)[(row + r) * ldc + col] = f2bf(acc[mf][nf][r]);
      }
    }
}

// ---------------------------------------------------------------------------
// 128x128-tile GEMM (proven R0-R3 kernel): C = A[M,K] * B[N,K]^T, bf16 out.
// Used for the KV slice of K1 (N=1024 -> 256 blocks, 2/CU, exactly 1 round).
// ---------------------------------------------------------------------------
template <bool OUT_F32>
__global__ __launch_bounds__(256) void gemm_bt_bf16(
    const unsigned short* __restrict__ A, const unsigned short* __restrict__ B,
    void* __restrict__ Cv, int lda, int ldb, int ldc, int K) {
  __shared__ alignas(16) unsigned short As[128 * 32];
  __shared__ alignas(16) unsigned short Bs[128 * 32];

  const int t    = threadIdx.x;
  const int lane = t & 63;
  const int w    = t >> 6;
  const int wm   = (w >> 1) * 64;
  const int wn   = (w & 1) * 64;
  const size_t m0 = (size_t)blockIdx.y * 128;
  const size_t n0 = (size_t)blockIdx.x * 128;

  f32x4 acc[4][4] = {};

  const int srow = w * 32 + (lane >> 2);
  const int scol = (lane & 3) * 8;
  const unsigned short* gA0 = &A[(m0 + srow) * (size_t)lda + scol];
  const unsigned short* gA1 = gA0 + 16 * (size_t)lda;
  const unsigned short* gB0 = &B[(n0 + srow) * (size_t)ldb + scol];
  const unsigned short* gB1 = gB0 + 16 * (size_t)ldb;
  unsigned short* lA0 = &As[(w * 32) * 32];
  unsigned short* lA1 = &As[(w * 32 + 16) * 32];
  unsigned short* lB0 = &Bs[(w * 32) * 32];
  unsigned short* lB1 = &Bs[(w * 32 + 16) * 32];

  const int fr = lane & 15;
  const int kb = (lane >> 4) * 8;

  for (int k0 = 0; k0 < K; k0 += 32) {
    load_lds16(gA0 + k0, lA0);
    load_lds16(gA1 + k0, lA1);
    load_lds16(gB0 + k0, lB0);
    load_lds16(gB1 + k0, lB1);
    __syncthreads();
    short8 af[4], bf[4];
#pragma unroll
    for (int mt = 0; mt < 4; mt++) af[mt] = *(const short8*)&As[(wm + mt * 16 + fr) * 32 + kb];
#pragma unroll
    for (int nt = 0; nt < 4; nt++) bf[nt] = *(const short8*)&Bs[(wn + nt * 16 + fr) * 32 + kb];
#pragma unroll
    for (int mt = 0; mt < 4; mt++)
#pragma unroll
      for (int nt = 0; nt < 4; nt++)
        acc[mt][nt] = __builtin_amdgcn_mfma_f32_16x16x32_bf16(af[mt], bf[nt], acc[mt][nt], 0, 0, 0);
    __syncthreads();
  }

  const int r4 = (lane >> 4) * 4;
  const int cc = lane & 15;
#pragma unroll
  for (int mt = 0; mt < 4; mt++)
#pragma unroll
    for (int nt = 0; nt < 4; nt++) {
      size_t row = m0 + wm + mt * 16 + r4;
      size_t col = n0 + wn + nt * 16 + cc;
#pragma unroll
      for (int r = 0; r < 4; r++) {
        if (OUT_F32) ((float*)Cv)[(row + r) * ldc + col] = acc[mt][nt][r];
        else ((unsigned short*)Cv)[(row + r) * ldc + col] = f2bf(acc[mt][nt][r]);
      }
    }
}

// ---------------------------------------------------------------------------
// RoPE cos/sin table per token: tab[tok*64+j] = {cos,sin}(pos[tok]*invfreq_j).
// ---------------------------------------------------------------------------
__global__ __launch_bounds__(64) void rope_tab(const int* __restrict__ pos,
                                               float2* __restrict__ tab) {
  const int tok = blockIdx.x;
  const int j = threadIdx.x;
  float p = (float)pos[tok];
  float inv_freq = expf((float)j * (-13.815510557964274f / 64.0f));  // 1e6^(-j/64)
  float ang = p * inv_freq;
  float2 cs; cs.x = cosf(ang); cs.y = sinf(ang);
  tab[tok * 64 + j] = cs;
}

// ---------------------------------------------------------------------------
// RMSNorm + RoPE, IN PLACE on qkv. 256 thr = 4 waves = 4 heads per block.
// ---------------------------------------------------------------------------
__global__ __launch_bounds__(256) void normrope(
    unsigned short* __restrict__ qkv, const float2* __restrict__ tab,
    const unsigned short* __restrict__ qw, const unsigned short* __restrict__ kw) {
  const int wv   = threadIdx.x >> 6;
  const int lane = threadIdx.x & 63;
  const int h    = blockIdx.x * 4 + wv;              // 0..35 (32 q + 4 k)
  const int tok  = blockIdx.z * SEQ + blockIdx.y;

  const unsigned short* w = (h < NH) ? qw : kw;
  const size_t src = (size_t)tok * QKV_O + (size_t)h * HD;

  float x1 = bf2f(qkv[src + lane]);
  float x2 = bf2f(qkv[src + lane + 64]);
  float ss = x1 * x1 + x2 * x2;
#pragma unroll
  for (int off = 32; off; off >>= 1) ss += __shfl_xor(ss, off);
  float r = rsqrtf(ss * (1.0f / 128.0f) + 1e-6f);
  float n1 = x1 * r * bf2f(w[lane]);
  float n2 = x2 * r * bf2f(w[lane + 64]);

  float2 cs = tab[tok * 64 + lane];
  qkv[src + lane]      = f2bf(n1 * cs.x - n2 * cs.y);
  qkv[src + lane + 64] = f2bf(n2 * cs.x + n1 * cs.y);
}

// ---------------------------------------------------------------------------
// V transpose: vt[b][kvh][d][s] <- qkv v-slot. One block per (kv-tile 64, kvh, b).
// ---------------------------------------------------------------------------
__global__ __launch_bounds__(256) void transpose_v(const unsigned short* __restrict__ qkv,
                                                   unsigned short* __restrict__ vt) {
  __shared__ alignas(16) unsigned short Vs[64][136];
  const int k0 = blockIdx.x * 64, kvh = blockIdx.y, b = blockIdx.z;
  const int t = threadIdx.x;
  const int voff = (NH + NKV) * HD + kvh * HD;
  {
    const int row = t >> 2, cb = (t & 3) * 8;
    const size_t gb = (size_t)(b * SEQ + k0 + row) * QKV_O + voff;
#pragma unroll
    for (int r = 0; r < 4; r++)
      *(uint4*)&Vs[row][cb + 32 * r] = *(const uint4*)&qkv[gb + cb + 32 * r];
  }
  __syncthreads();
  const int d = t >> 1, half = t & 1;
  const size_t ob = ((size_t)((b * NKV + kvh) * HD + d)) * SEQ + k0 + half * 32;
#pragma unroll
  for (int i = 0; i < 4; i++) {
    u16x8 vv;
#pragma unroll
    for (int j = 0; j < 8; j++) vv[j] = Vs[half * 32 + i * 8 + j][d];
    *(u16x8*)&vt[ob + i * 8] = vv;
  }
}

// ---------------------------------------------------------------------------
// MFMA causal GQA flash attention (v5, unchanged from R2/R3).
// ---------------------------------------------------------------------------
__global__ __launch_bounds__(512, 4) void flash_mfma(unsigned short* __restrict__ qkv,
                                                     const unsigned short* __restrict__ vt) {
  __shared__ alignas(16) unsigned short Kbuf[2][64 * 128];
  __shared__ alignas(16) unsigned short Vbuf[2][128 * 64];
  __shared__ alignas(16) unsigned short Ps[8][16 * 64];

  const int p = (int)blockIdx.x;                       // pair index 0..7
  const int h = blockIdx.y, b = blockIdx.z;
  const int t = threadIdx.x;
  const int lane = t & 63, w = t >> 6;
  const int c = lane & 15, g = lane >> 4;
  const int kvh = h >> 3;                              // GQA 32->4
  const int koff = NH * HD + kvh * HD;
  const float scale = 0.08838834764831845f;            // 128^-0.5
  const int swz = c & 7;                               // 3-bit swz (V, P tiles)
  const int nqt = SEQ / 128;                           // 16

  const int rK0 = t >> 4,         jK0 = (t & 15) ^ (rK0 & 15);
  const int rK1 = (t + 512) >> 4, jK1 = ((t + 512) & 15) ^ (rK1 & 15);
  const int dV0 = t >> 3,         jV0 = (t & 7) ^ (dV0 & 7);
  const int dV1 = (t + 512) >> 3, jV1 = ((t + 512) & 7) ^ (dV1 & 7);
  const unsigned short* gK0 = qkv + (size_t)(b * SEQ + rK0) * QKV_O + koff + jK0 * 8;
  const unsigned short* gK1 = qkv + (size_t)(b * SEQ + rK1) * QKV_O + koff + jK1 * 8;
  const unsigned short* gV0 = vt + ((size_t)(b * NKV + kvh) * HD + dV0) * SEQ + jV0 * 8;
  const unsigned short* gV1 = vt + ((size_t)(b * NKV + kvh) * HD + dV1) * SEQ + jV1 * 8;

  auto stage = [&](int k0s, int bi) {
    load_lds16(gK0 + (size_t)k0s * QKV_O, &Kbuf[bi][(w * 64) * 8]);
    load_lds16(gK1 + (size_t)k0s * QKV_O, &Kbuf[bi][(w * 64 + 512) * 8]);
    load_lds16(gV0 + k0s, &Vbuf[bi][(w * 64) * 8]);
    load_lds16(gV1 + k0s, &Vbuf[bi][(w * 64 + 512) * 8]);
  };

  for (int job = 0; job < 2; job++) {
    const int qt = job == 0 ? (nqt - 1 - p) : p;       // heavy job first
    const int q0 = qt * 128;
    const int nkt = 2 * qt + 2;

    stage(0, 0);   // prologue: tile 0 -> buf 0

    short8 qf[4];
    {
      const size_t qr = (size_t)(b * SEQ + q0 + w * 16 + c) * QKV_O + (size_t)h * HD;
#pragma unroll
      for (int ks = 0; ks < 4; ks++)
        qf[ks] = *(const short8*)&qkv[qr + ks * 32 + g * 8];
    }

    f32x4 O[8] = {};
    float m_i = -1e30f, l_i = 0.0f;

    for (int kt = 0; kt < nkt; kt++) {
      const int cur = kt & 1;
      asm volatile("s_waitcnt vmcnt(0)" ::: "memory");
      __builtin_amdgcn_s_barrier();
      __builtin_amdgcn_sched_barrier(0);
      if (kt + 1 < nkt) stage((kt + 1) * 64, cur ^ 1);

      const unsigned short* Kc = Kbuf[cur];
      const unsigned short* Vc = Vbuf[cur];

      f32x4 sc[4];
#pragma unroll
      for (int mt = 0; mt < 4; mt++) sc[mt] = (f32x4){0.f, 0.f, 0.f, 0.f};
      __builtin_amdgcn_s_setprio(1);
#pragma unroll
      for (int ks = 0; ks < 4; ks++) {
#pragma unroll
        for (int mt = 0; mt < 4; mt++) {
          short8 kf = *(const short8*)&Kc[(mt * 16 + c) * 128 + (((ks * 4 + g) ^ c) * 8)];
          sc[mt] = __builtin_amdgcn_mfma_f32_16x16x32_bf16(kf, qf[ks], sc[mt], 0, 0, 0);
        }
      }
      __builtin_amdgcn_s_setprio(0);

      const int k0 = kt * 64;
      const int qrow = q0 + w * 16 + c;
      const bool need_mask = (k0 + 63 > q0 + w * 16);
      float mx = -3.0e38f;
#pragma unroll
      for (int mt = 0; mt < 4; mt++)
#pragma unroll
        for (int r = 0; r < 4; r++) {
          float s = sc[mt][r];
          if (need_mask && (k0 + mt * 16 + g * 4 + r > qrow)) s = -3.0e38f;
          sc[mt][r] = s;
          mx = fmaxf(mx, s);
        }
      mx = fmaxf(mx, __shfl_xor(mx, 16));
      mx = fmaxf(mx, __shfl_xor(mx, 32));
      float mxs = mx * scale;

      if (!__all(mxs - m_i <= 8.0f)) {
        float m_new = fmaxf(m_i, mxs);
        float alpha = __expf(m_i - m_new);
        f32x4 a4;
#pragma unroll
        for (int r = 0; r < 4; r++) a4[r] = __shfl(alpha, g * 4 + r);
#pragma unroll
        for (int nt = 0; nt < 8; nt++)
#pragma unroll
          for (int r = 0; r < 4; r++) O[nt][r] *= a4[r];
        l_i *= alpha;
        m_i = m_new;
      }

      float psum = 0.0f;
#pragma unroll
      for (int mt = 0; mt < 4; mt++) {
        u16x4 p4;
#pragma unroll
        for (int r = 0; r < 4; r++) {
          float pv = __expf(__builtin_fmaf(sc[mt][r], scale, -m_i));
          psum += pv;
          p4[r] = f2bf(pv);
        }
        *(u16x4*)&Ps[w][c * 64 + (((mt * 2 + (g >> 1)) ^ swz) * 8) + (g & 1) * 4] = p4;
      }
      psum += __shfl_xor(psum, 16);
      psum += __shfl_xor(psum, 32);
      l_i += psum;

      __builtin_amdgcn_s_setprio(1);
#pragma unroll
      for (int ks = 0; ks < 2; ks++) {
        short8 pf = *(const short8*)&Ps[w][c * 64 + (((ks * 4 + g) ^ swz) * 8)];
#pragma unroll
        for (int nt = 0; nt < 8; nt++) {
          short8 vf = *(const short8*)&Vc[(nt * 16 + c) * 64 + (((ks * 4 + g) ^ swz) * 8)];
          O[nt] = __builtin_amdgcn_mfma_f32_16x16x32_bf16(pf, vf, O[nt], 0, 0, 0);
        }
      }
      __builtin_amdgcn_s_setprio(0);
    }

    f32x4 l4;
#pragma unroll
    for (int r = 0; r < 4; r++) l4[r] = __shfl(l_i, g * 4 + r);
    f32x4 li;
#pragma unroll
    for (int r = 0; r < 4; r++) li[r] = 1.0f / l4[r];
#pragma unroll
    for (int nt = 0; nt < 8; nt++)
#pragma unroll
      for (int r = 0; r < 4; r++) {
        size_t addr = (size_t)(b * SEQ + q0 + w * 16 + g * 4 + r) * QKV_O + h * HD + nt * 16 + c;
        qkv[addr] = f2bf(O[nt][r] * li[r]);
      }
  }
}

// ---------------------------------------------------------------------------
extern "C" void kernel_launch(void* const* d_in, const int* in_sizes, int n_in,
                              void* d_out, int out_size, void* d_ws, size_t ws_size,
                              hipStream_t stream) {
  const float* hidden_f = (const float*)d_in[0];
  const int* positions  = (const int*)d_in[1];
  const float* wqkv_f   = (const float*)d_in[2];
  const float* wo_f     = (const float*)d_in[3];
  const float* qn_f     = (const float*)d_in[4];
  const float* kn_f     = (const float*)d_in[5];
  float* out            = (float*)d_out;  // reference output dtype is float32

  char* ws = (char*)d_ws;
  unsigned short* hidden_c = (unsigned short*)ws;                    // 16,777,216
  unsigned short* wqkv_c   = (unsigned short*)(ws + 16777216);       // 20,971,520
  unsigned short* wo_c     = (unsigned short*)(ws + 37748736);       // 16,777,216
  unsigned short* qn_c     = (unsigned short*)(ws + 54525952);       // 256
  unsigned short* kn_c     = (unsigned short*)(ws + 54526208);       // 256
  unsigned short* qkv      = (unsigned short*)(ws + 54526464);       // 41,943,040
  unsigned short* vt_g     = (unsigned short*)(ws + 96469504);       // 4,194,304  (total ~96 MiB)
  // rope table REUSES the hidden_c region (dead after K1): 2 MiB
  float2* rtab             = (float2*)ws;
  // split-K fp32 partial for K4 (4096x2048x4 = 33.5 MB) overlays the dead
  // hidden_c+wqkv_c regions (33.5 < 37.7 MB, doesn't touch wo_c)
  float* p0                = (float*)ws;

  convert_to_bf16<<<1024, 256, 0, stream>>>(hidden_f, hidden_c, NTOK * HID / 4);
  convert_to_bf16<<<1024, 256, 0, stream>>>(wqkv_f, wqkv_c, QKV_O * HID / 4);
  convert_to_bf16<<<1024, 256, 0, stream>>>(wo_f, wo_c, HID * NH * HD / 4);
  convert_to_bf16<<<1, 32, 0, stream>>>(qn_f, qn_c, HD / 4);
  convert_to_bf16<<<1, 32, 0, stream>>>(kn_f, kn_c, HD / 4);

  // K1a: Q slice: qkv[:, :4096] = hidden @ w_qkv[:4096]^T  (4096x4096, K=2048)
  // 16x16 = 256 blocks = exactly 1 round at 1 block/CU.
  gemm256_p4<false, false><<<dim3(NH * HD / 256, NTOK / 256), 512, 0, stream>>>(
      hidden_c, wqkv_c, qkv, qkv, HID, HID, QKV_O, HID);
  // K1b: KV slice: qkv[:, 4096:5120] = hidden @ w_qkv[4096:]^T (4096x1024)
  // 8x32 = 256 blocks = 1 round at 2 blocks/CU on the 128^2 kernel.
  gemm_bt_bf16<false><<<dim3(2 * NKV * HD / 128, NTOK / 128), 256, 0, stream>>>(
      hidden_c, wqkv_c + (size_t)(NH * HD) * HID, qkv + NH * HD, HID, HID, QKV_O, HID);
  // K1c: rope table (hidden_c dead now; table overwrites it)
  rope_tab<<<NTOK, 64, 0, stream>>>(positions, rtab);
  // K2: rmsnorm + rope, in place on q & k head slots (4 heads/block)
  normrope<<<dim3((NH + NKV) / 4, SEQ, BATCH), 256, 0, stream>>>(qkv, rtab, qn_c, kn_c);
  // K2b: V transpose into vt_g
  transpose_v<<<dim3(SEQ / 64, NKV, BATCH), 256, 0, stream>>>(qkv, vt_g);
  // K3: MFMA causal GQA attention (v5)
  flash_mfma<<<dim3(SEQ / 256, NH, BATCH), 512, 0, stream>>>(qkv, vt_g);
  // K4: out = attn @ w_o^T (4096 x 2048, K=4096), split-K=2 -> 256 blocks:
  // z=0 -> p0 (fp32 partial, k 0..2047), z=1 -> out (k 2048..4095)
  gemm256_p4<true, true><<<dim3(HID / 256, NTOK / 256, 2), 512, 0, stream>>>(
      qkv, wo_c, p0, out, QKV_O, NH * HD, HID, NH * HD / 2);
  // K4b: out += p0
  reduce_add<<<2048, 256, 0, stream>>>(out, p0, NTOK * HID / 4);
}

// Round 6
// 468.049 us; speedup vs baseline: 1.0964x; 1.0964x over previous
//
#include <hip/hip_runtime.h>
#include <cstdint>

#define SEQ 2048
#define BATCH 2
#define NTOK 4096      // B*S
#define HID 2048
#define NH 32
#define NKV 4
#define HD 128
#define QKV_O 5120     // (32+8)*128

typedef __attribute__((ext_vector_type(8))) short short8;
typedef __attribute__((ext_vector_type(8))) unsigned short u16x8;
typedef __attribute__((ext_vector_type(4))) unsigned short u16x4;
typedef __attribute__((ext_vector_type(4))) float f32x4;

__device__ __forceinline__ float bf2f(unsigned short u) {
  union { unsigned int i; float f; } v; v.i = ((unsigned int)u) << 16; return v.f;
}
__device__ __forceinline__ unsigned short f2bf(float f) {
  union { float f; unsigned int i; } v; v.f = f;
  unsigned int r = v.i + 0x7FFFu + ((v.i >> 16) & 1u);
  return (unsigned short)(r >> 16);
}

// async global->LDS, 16 B per lane. LDS dest is wave-uniform base + lane*16.
__device__ __forceinline__ void load_lds16(const void* g, void* l) {
  __builtin_amdgcn_global_load_lds((const __attribute__((address_space(1))) unsigned int*)g,
                                   (__attribute__((address_space(3))) unsigned int*)l, 16, 0, 0);
}

// ---------------------------------------------------------------------------
// fp32 -> bf16 (round-to-nearest-even), vectorized. n4 = n/4.
// ---------------------------------------------------------------------------
__global__ __launch_bounds__(256) void convert_to_bf16(const float* __restrict__ src,
                                                       unsigned short* __restrict__ dst,
                                                       int n4) {
  int i = blockIdx.x * blockDim.x + threadIdx.x;
  int stride = gridDim.x * blockDim.x;
  for (; i < n4; i += stride) {
    f32x4 v = *(const f32x4*)(src + 4 * (size_t)i);
    u16x4 o;
    o.x = f2bf(v.x); o.y = f2bf(v.y); o.z = f2bf(v.z); o.w = f2bf(v.w);
    *(u16x4*)(dst + 4 * (size_t)i) = o;
  }
}

// ---------------------------------------------------------------------------
// out4 += part4 (fp32), grid-stride. Reduce for split-K.
// ---------------------------------------------------------------------------
__global__ __launch_bounds__(256) void reduce_add(float* __restrict__ out,
                                                  const float* __restrict__ part, int n4) {
  int i = blockIdx.x * blockDim.x + threadIdx.x;
  int stride = gridDim.x * blockDim.x;
  for (; i < n4; i += stride) {
    f32x4 a = *(const f32x4*)(out + 4 * (size_t)i);
    f32x4 b = *(const f32x4*)(part + 4 * (size_t)i);
    a.x += b.x; a.y += b.y; a.z += b.z; a.w += b.w;
    *(f32x4*)(out + 4 * (size_t)i) = a;
  }
}

// ---------------------------------------------------------------------------
// 256x256-tile GEMM (R3-proven): C[M,N] = A[M,K] * B[N,K]^T, bf16 in, fp32 acc.
// BK=64, 512 thr (8 waves, 2M x 4N), per-wave output 128x64 (8x4 frags).
// Double-buffered 128 KiB LDS via global_load_lds(16B): linear LDS dest +
// inverse-XOR-swizzled source + XOR-swizzled ds_read_b128 (chunk ^= row&7;
// rows are 128 B = full bank line -> measured SQ_LDS_BANK_CONFLICT = 0).
// One vmcnt(0)+s_barrier per K-tile; next tile staged under 64 MFMAs.
// SPLIT: gridDim.z=2 halves K; z=0 -> C0 (fp32 partial), z=1 -> C1.
// ---------------------------------------------------------------------------
template <bool OUT_F32, bool SPLIT>
__global__ __launch_bounds__(512, 2) void gemm256(
    const unsigned short* __restrict__ A, const unsigned short* __restrict__ B,
    void* __restrict__ C0, void* __restrict__ C1,
    int lda, int ldb, int ldc, int Kloop) {
  __shared__ alignas(16) unsigned short As[2][256 * 64];
  __shared__ alignas(16) unsigned short Bs[2][256 * 64];

  const int t = threadIdx.x;
  const int lane = t & 63, w = t >> 6;
  const int fr = lane & 15, g = lane >> 4;
  const int wm = w >> 2, wn = w & 3;                 // 2 x 4 wave grid
  const size_t m0 = (size_t)blockIdx.y * 256;
  const size_t n0 = (size_t)blockIdx.x * 256;
  const int kbase = SPLIT ? (int)blockIdx.z * Kloop : 0;
  void* Cv = (SPLIT && blockIdx.z) ? C1 : C0;

  // staging: thread t owns slots s = i*512 + w*64 + lane (i=0..3) per tile.
  // LDS row = s>>3, chunk = lane&7; source chunk = (lane&7) ^ (row&7).
  const int srow = w * 8 + (lane >> 3);
  const int sch = (lane & 7) ^ ((lane >> 3) & 7);
  const unsigned short* gA[4];
  const unsigned short* gB[4];
#pragma unroll
  for (int i = 0; i < 4; i++) {
    gA[i] = A + (m0 + i * 64 + srow) * (size_t)lda + kbase + sch * 8;
    gB[i] = B + (n0 + i * 64 + srow) * (size_t)ldb + kbase + sch * 8;
  }

  auto stage = [&](int k0, int bi) {
#pragma unroll
    for (int i = 0; i < 4; i++) {
      load_lds16(gA[i] + k0, &As[bi][(i * 512 + w * 64) * 8]);
      load_lds16(gB[i] + k0, &Bs[bi][(i * 512 + w * 64) * 8]);
    }
  };

  f32x4 acc[8][4] = {};
  stage(0, 0);

  const int nk = Kloop / 64;
  for (int kt = 0; kt < nk; kt++) {
    const int cur = kt & 1;
    asm volatile("s_waitcnt vmcnt(0)" ::: "memory");
    __builtin_amdgcn_s_barrier();
    __builtin_amdgcn_sched_barrier(0);
    if (kt + 1 < nk) stage((kt + 1) * 64, cur ^ 1);

    const unsigned short* Ac = As[cur];
    const unsigned short* Bc = Bs[cur];

    // B frags: 4 n-frags x 2 k-subtiles (swizzled chunk = (s*4+g) ^ (fr&7))
    short8 bfr[4][2];
#pragma unroll
    for (int nf = 0; nf < 4; nf++) {
      const int row = wn * 64 + nf * 16 + fr;
#pragma unroll
      for (int s = 0; s < 2; s++)
        bfr[nf][s] = *(const short8*)&Bc[row * 64 + (((s * 4 + g) ^ (fr & 7)) * 8)];
    }
    __builtin_amdgcn_s_setprio(1);
#pragma unroll
    for (int mf = 0; mf < 8; mf++) {
      const int row = wm * 128 + mf * 16 + fr;
      short8 af0 = *(const short8*)&Ac[row * 64 + (((0 + g) ^ (fr & 7)) * 8)];
      short8 af1 = *(const short8*)&Ac[row * 64 + (((4 + g) ^ (fr & 7)) * 8)];
#pragma unroll
      for (int nf = 0; nf < 4; nf++) {
        acc[mf][nf] = __builtin_amdgcn_mfma_f32_16x16x32_bf16(af0, bfr[nf][0], acc[mf][nf], 0, 0, 0);
        acc[mf][nf] = __builtin_amdgcn_mfma_f32_16x16x32_bf16(af1, bfr[nf][1], acc[mf][nf], 0, 0, 0);
      }
    }
    __builtin_amdgcn_s_setprio(0);
  }

  // epilogue: C/D layout col=lane&15, row=(lane>>4)*4+reg
#pragma unroll
  for (int mf = 0; mf < 8; mf++)
#pragma unroll
    for (int nf = 0; nf < 4; nf++) {
      size_t row = m0 + wm * 128 + mf * 16 + g * 4;
      size_t col = n0 + wn * 64 + nf * 16 + fr;
#pragma unroll
      for (int r = 0; r < 4; r++) {
        if (OUT_F32) ((float*)Cv)[(row + r) * ldc + col] = acc[mf][nf][r];
        else ((unsigned short*)Cv)[(row + r) * ldc + col] = f2bf(acc[mf][nf][r]);
      }
    }
}

// ---------------------------------------------------------------------------
// 128x128-tile GEMM (proven R0-R3): C = A[M,K] * B[N,K]^T.
// Used for the KV slice of K1 (N=1024 -> 256 blocks, 2/CU, exactly 1 round).
// ---------------------------------------------------------------------------
template <bool OUT_F32>
__global__ __launch_bounds__(256) void gemm_bt_bf16(
    const unsigned short* __restrict__ A, const unsigned short* __restrict__ B,
    void* __restrict__ Cv, int lda, int ldb, int ldc, int K) {
  __shared__ alignas(16) unsigned short As[128 * 32];
  __shared__ alignas(16) unsigned short Bs[128 * 32];

  const int t    = threadIdx.x;
  const int lane = t & 63;
  const int w    = t >> 6;
  const int wm   = (w >> 1) * 64;
  const int wn   = (w & 1) * 64;
  const size_t m0 = (size_t)blockIdx.y * 128;
  const size_t n0 = (size_t)blockIdx.x * 128;

  f32x4 acc[4][4] = {};

  const int srow = w * 32 + (lane >> 2);
  const int scol = (lane & 3) * 8;
  const unsigned short* gA0 = &A[(m0 + srow) * (size_t)lda + scol];
  const unsigned short* gA1 = gA0 + 16 * (size_t)lda;
  const unsigned short* gB0 = &B[(n0 + srow) * (size_t)ldb + scol];
  const unsigned short* gB1 = gB0 + 16 * (size_t)ldb;
  unsigned short* lA0 = &As[(w * 32) * 32];
  unsigned short* lA1 = &As[(w * 32 + 16) * 32];
  unsigned short* lB0 = &Bs[(w * 32) * 32];
  unsigned short* lB1 = &Bs[(w * 32 + 16) * 32];

  const int fr = lane & 15;
  const int kb = (lane >> 4) * 8;

  for (int k0 = 0; k0 < K; k0 += 32) {
    load_lds16(gA0 + k0, lA0);
    load_lds16(gA1 + k0, lA1);
    load_lds16(gB0 + k0, lB0);
    load_lds16(gB1 + k0, lB1);
    __syncthreads();
    short8 af[4], bf[4];
#pragma unroll
    for (int mt = 0; mt < 4; mt++) af[mt] = *(const short8*)&As[(wm + mt * 16 + fr) * 32 + kb];
#pragma unroll
    for (int nt = 0; nt < 4; nt++) bf[nt] = *(const short8*)&Bs[(wn + nt * 16 + fr) * 32 + kb];
#pragma unroll
    for (int mt = 0; mt < 4; mt++)
#pragma unroll
      for (int nt = 0; nt < 4; nt++)
        acc[mt][nt] = __builtin_amdgcn_mfma_f32_16x16x32_bf16(af[mt], bf[nt], acc[mt][nt], 0, 0, 0);
    __syncthreads();
  }

  const int r4 = (lane >> 4) * 4;
  const int cc = lane & 15;
#pragma unroll
  for (int mt = 0; mt < 4; mt++)
#pragma unroll
    for (int nt = 0; nt < 4; nt++) {
      size_t row = m0 + wm + mt * 16 + r4;
      size_t col = n0 + wn + nt * 16 + cc;
#pragma unroll
      for (int r = 0; r < 4; r++) {
        if (OUT_F32) ((float*)Cv)[(row + r) * ldc + col] = acc[mt][nt][r];
        else ((unsigned short*)Cv)[(row + r) * ldc + col] = f2bf(acc[mt][nt][r]);
      }
    }
}

// ---------------------------------------------------------------------------
// RoPE cos/sin table per token: tab[tok*64+j] = {cos,sin}(pos[tok]*invfreq_j).
// ---------------------------------------------------------------------------
__global__ __launch_bounds__(64) void rope_tab(const int* __restrict__ pos,
                                               float2* __restrict__ tab) {
  const int tok = blockIdx.x;
  const int j = threadIdx.x;
  float p = (float)pos[tok];
  float inv_freq = expf((float)j * (-13.815510557964274f / 64.0f));  // 1e6^(-j/64)
  float ang = p * inv_freq;
  float2 cs; cs.x = cosf(ang); cs.y = sinf(ang);
  tab[tok * 64 + j] = cs;
}

// ---------------------------------------------------------------------------
// RMSNorm + RoPE, IN PLACE on qkv. 256 thr = 4 waves = 4 heads per block.
// ---------------------------------------------------------------------------
__global__ __launch_bounds__(256) void normrope(
    unsigned short* __restrict__ qkv, const float2* __restrict__ tab,
    const unsigned short* __restrict__ qw, const unsigned short* __restrict__ kw) {
  const int wv   = threadIdx.x >> 6;
  const int lane = threadIdx.x & 63;
  const int h    = blockIdx.x * 4 + wv;              // 0..35 (32 q + 4 k)
  const int tok  = blockIdx.z * SEQ + blockIdx.y;

  const unsigned short* w = (h < NH) ? qw : kw;
  const size_t src = (size_t)tok * QKV_O + (size_t)h * HD;

  float x1 = bf2f(qkv[src + lane]);
  float x2 = bf2f(qkv[src + lane + 64]);
  float ss = x1 * x1 + x2 * x2;
#pragma unroll
  for (int off = 32; off; off >>= 1) ss += __shfl_xor(ss, off);
  float r = rsqrtf(ss * (1.0f / 128.0f) + 1e-6f);
  float n1 = x1 * r * bf2f(w[lane]);
  float n2 = x2 * r * bf2f(w[lane + 64]);

  float2 cs = tab[tok * 64 + lane];
  qkv[src + lane]      = f2bf(n1 * cs.x - n2 * cs.y);
  qkv[src + lane + 64] = f2bf(n2 * cs.x + n1 * cs.y);
}

// ---------------------------------------------------------------------------
// V transpose: vt[b][kvh][d][s] <- qkv v-slot. One block per (kv-tile 64, kvh, b).
// ---------------------------------------------------------------------------
__global__ __launch_bounds__(256) void transpose_v(const unsigned short* __restrict__ qkv,
                                                   unsigned short* __restrict__ vt) {
  __shared__ alignas(16) unsigned short Vs[64][136];
  const int k0 = blockIdx.x * 64, kvh = blockIdx.y, b = blockIdx.z;
  const int t = threadIdx.x;
  const int voff = (NH + NKV) * HD + kvh * HD;
  {
    const int row = t >> 2, cb = (t & 3) * 8;
    const size_t gb = (size_t)(b * SEQ + k0 + row) * QKV_O + voff;
#pragma unroll
    for (int r = 0; r < 4; r++)
      *(uint4*)&Vs[row][cb + 32 * r] = *(const uint4*)&qkv[gb + cb + 32 * r];
  }
  __syncthreads();
  const int d = t >> 1, half = t & 1;
  const size_t ob = ((size_t)((b * NKV + kvh) * HD + d)) * SEQ + k0 + half * 32;
#pragma unroll
  for (int i = 0; i < 4; i++) {
    u16x8 vv;
#pragma unroll
    for (int j = 0; j < 8; j++) vv[j] = Vs[half * 32 + i * 8 + j][d];
    *(u16x8*)&vt[ob + i * 8] = vv;
  }
}

// ---------------------------------------------------------------------------
// MFMA causal GQA flash attention (v6 = v5 + cvt_pk P-pack).
// 512 thr, Q-tile 128, diag-paired jobs, dbuf global_load_lds staging,
// one barrier+vmcnt(0)/tile, 4-bit K swizzle, fmaf-exp, defer-max.
// v6: P-pack uses v_cvt_pk_bf16_f32 (8 asm ops) instead of 16 manual f2bf
// (~64 VALU bit-ops) -- kernel is VALU-limited (52% VALUBusy).
// ---------------------------------------------------------------------------
__global__ __launch_bounds__(512, 4) void flash_mfma(unsigned short* __restrict__ qkv,
                                                     const unsigned short* __restrict__ vt) {
  __shared__ alignas(16) unsigned short Kbuf[2][64 * 128];
  __shared__ alignas(16) unsigned short Vbuf[2][128 * 64];
  __shared__ alignas(16) unsigned short Ps[8][16 * 64];

  const int p = (int)blockIdx.x;                       // pair index 0..7
  const int h = blockIdx.y, b = blockIdx.z;
  const int t = threadIdx.x;
  const int lane = t & 63, w = t >> 6;
  const int c = lane & 15, g = lane >> 4;
  const int kvh = h >> 3;                              // GQA 32->4
  const int koff = NH * HD + kvh * HD;
  const float scale = 0.08838834764831845f;            // 128^-0.5
  const int swz = c & 7;                               // 3-bit swz (V, P tiles)
  const int nqt = SEQ / 128;                           // 16

  const int rK0 = t >> 4,         jK0 = (t & 15) ^ (rK0 & 15);
  const int rK1 = (t + 512) >> 4, jK1 = ((t + 512) & 15) ^ (rK1 & 15);
  const int dV0 = t >> 3,         jV0 = (t & 7) ^ (dV0 & 7);
  const int dV1 = (t + 512) >> 3, jV1 = ((t + 512) & 7) ^ (dV1 & 7);
  const unsigned short* gK0 = qkv + (size_t)(b * SEQ + rK0) * QKV_O + koff + jK0 * 8;
  const unsigned short* gK1 = qkv + (size_t)(b * SEQ + rK1) * QKV_O + koff + jK1 * 8;
  const unsigned short* gV0 = vt + ((size_t)(b * NKV + kvh) * HD + dV0) * SEQ + jV0 * 8;
  const unsigned short* gV1 = vt + ((size_t)(b * NKV + kvh) * HD + dV1) * SEQ + jV1 * 8;

  auto stage = [&](int k0s, int bi) {
    load_lds16(gK0 + (size_t)k0s * QKV_O, &Kbuf[bi][(w * 64) * 8]);
    load_lds16(gK1 + (size_t)k0s * QKV_O, &Kbuf[bi][(w * 64 + 512) * 8]);
    load_lds16(gV0 + k0s, &Vbuf[bi][(w * 64) * 8]);
    load_lds16(gV1 + k0s, &Vbuf[bi][(w * 64 + 512) * 8]);
  };

  for (int job = 0; job < 2; job++) {
    const int qt = job == 0 ? (nqt - 1 - p) : p;       // heavy job first
    const int q0 = qt * 128;
    const int nkt = 2 * qt + 2;

    stage(0, 0);   // prologue: tile 0 -> buf 0

    short8 qf[4];
    {
      const size_t qr = (size_t)(b * SEQ + q0 + w * 16 + c) * QKV_O + (size_t)h * HD;
#pragma unroll
      for (int ks = 0; ks < 4; ks++)
        qf[ks] = *(const short8*)&qkv[qr + ks * 32 + g * 8];
    }

    f32x4 O[8] = {};
    float m_i = -1e30f, l_i = 0.0f;

    for (int kt = 0; kt < nkt; kt++) {
      const int cur = kt & 1;
      asm volatile("s_waitcnt vmcnt(0)" ::: "memory");
      __builtin_amdgcn_s_barrier();
      __builtin_amdgcn_sched_barrier(0);
      if (kt + 1 < nkt) stage((kt + 1) * 64, cur ^ 1);

      const unsigned short* Kc = Kbuf[cur];
      const unsigned short* Vc = Vbuf[cur];

      f32x4 sc[4];
#pragma unroll
      for (int mt = 0; mt < 4; mt++) sc[mt] = (f32x4){0.f, 0.f, 0.f, 0.f};
      __builtin_amdgcn_s_setprio(1);
#pragma unroll
      for (int ks = 0; ks < 4; ks++) {
#pragma unroll
        for (int mt = 0; mt < 4; mt++) {
          short8 kf = *(const short8*)&Kc[(mt * 16 + c) * 128 + (((ks * 4 + g) ^ c) * 8)];
          sc[mt] = __builtin_amdgcn_mfma_f32_16x16x32_bf16(kf, qf[ks], sc[mt], 0, 0, 0);
        }
      }
      __builtin_amdgcn_s_setprio(0);

      const int k0 = kt * 64;
      const int qrow = q0 + w * 16 + c;
      const bool need_mask = (k0 + 63 > q0 + w * 16);
      float mx = -3.0e38f;
#pragma unroll
      for (int mt = 0; mt < 4; mt++)
#pragma unroll
        for (int r = 0; r < 4; r++) {
          float s = sc[mt][r];
          if (need_mask && (k0 + mt * 16 + g * 4 + r > qrow)) s = -3.0e38f;
          sc[mt][r] = s;
          mx = fmaxf(mx, s);
        }
      mx = fmaxf(mx, __shfl_xor(mx, 16));
      mx = fmaxf(mx, __shfl_xor(mx, 32));
      float mxs = mx * scale;

      if (!__all(mxs - m_i <= 8.0f)) {
        float m_new = fmaxf(m_i, mxs);
        float alpha = __expf(m_i - m_new);
        f32x4 a4;
#pragma unroll
        for (int r = 0; r < 4; r++) a4[r] = __shfl(alpha, g * 4 + r);
#pragma unroll
        for (int nt = 0; nt < 8; nt++)
#pragma unroll
          for (int r = 0; r < 4; r++) O[nt][r] *= a4[r];
        l_i *= alpha;
        m_i = m_new;
      }

      float psum = 0.0f;
#pragma unroll
      for (int mt = 0; mt < 4; mt++) {
        float pv[4];
#pragma unroll
        for (int r = 0; r < 4; r++) {
          pv[r] = __expf(__builtin_fmaf(sc[mt][r], scale, -m_i));
          psum += pv[r];
        }
        unsigned int pk0, pk1;
        asm("v_cvt_pk_bf16_f32 %0, %1, %2" : "=v"(pk0) : "v"(pv[0]), "v"(pv[1]));
        asm("v_cvt_pk_bf16_f32 %0, %1, %2" : "=v"(pk1) : "v"(pv[2]), "v"(pv[3]));
        uint2 pk; pk.x = pk0; pk.y = pk1;
        *(uint2*)&Ps[w][c * 64 + (((mt * 2 + (g >> 1)) ^ swz) * 8) + (g & 1) * 4] = pk;
      }
      psum += __shfl_xor(psum, 16);
      psum += __shfl_xor(psum, 32);
      l_i += psum;

      __builtin_amdgcn_s_setprio(1);
#pragma unroll
      for (int ks = 0; ks < 2; ks++) {
        short8 pf = *(const short8*)&Ps[w][c * 64 + (((ks * 4 + g) ^ swz) * 8)];
#pragma unroll
        for (int nt = 0; nt < 8; nt++) {
          short8 vf = *(const short8*)&Vc[(nt * 16 + c) * 64 + (((ks * 4 + g) ^ swz) * 8)];
          O[nt] = __builtin_amdgcn_mfma_f32_16x16x32_bf16(pf, vf, O[nt], 0, 0, 0);
        }
      }
      __builtin_amdgcn_s_setprio(0);
    }

    f32x4 l4;
#pragma unroll
    for (int r = 0; r < 4; r++) l4[r] = __shfl(l_i, g * 4 + r);
    f32x4 li;
#pragma unroll
    for (int r = 0; r < 4; r++) li[r] = 1.0f / l4[r];
#pragma unroll
    for (int nt = 0; nt < 8; nt++)
#pragma unroll
      for (int r = 0; r < 4; r++) {
        size_t addr = (size_t)(b * SEQ + q0 + w * 16 + g * 4 + r) * QKV_O + h * HD + nt * 16 + c;
        qkv[addr] = f2bf(O[nt][r] * li[r]);
      }
  }
}

// ---------------------------------------------------------------------------
extern "C" void kernel_launch(void* const* d_in, const int* in_sizes, int n_in,
                              void* d_out, int out_size, void* d_ws, size_t ws_size,
                              hipStream_t stream) {
  const float* hidden_f = (const float*)d_in[0];
  const int* positions  = (const int*)d_in[1];
  const float* wqkv_f   = (const float*)d_in[2];
  const float* wo_f     = (const float*)d_in[3];
  const float* qn_f     = (const float*)d_in[4];
  const float* kn_f     = (const float*)d_in[5];
  float* out            = (float*)d_out;  // reference output dtype is float32

  char* ws = (char*)d_ws;
  unsigned short* hidden_c = (unsigned short*)ws;                    // 16,777,216
  unsigned short* wqkv_c   = (unsigned short*)(ws + 16777216);       // 20,971,520
  unsigned short* wo_c     = (unsigned short*)(ws + 37748736);       // 16,777,216
  unsigned short* qn_c     = (unsigned short*)(ws + 54525952);       // 256
  unsigned short* kn_c     = (unsigned short*)(ws + 54526208);       // 256
  unsigned short* qkv      = (unsigned short*)(ws + 54526464);       // 41,943,040
  unsigned short* vt_g     = (unsigned short*)(ws + 96469504);       // 4,194,304  (total ~96 MiB)
  // rope table REUSES the hidden_c region (dead after K1): 2 MiB
  float2* rtab             = (float2*)ws;
  // split-K fp32 partial for K4 (4096x2048x4 = 33.5 MB) overlays the dead
  // hidden_c+wqkv_c regions (33.5 < 37.7 MB, doesn't touch wo_c)
  float* p0                = (float*)ws;

  convert_to_bf16<<<1024, 256, 0, stream>>>(hidden_f, hidden_c, NTOK * HID / 4);
  convert_to_bf16<<<1024, 256, 0, stream>>>(wqkv_f, wqkv_c, QKV_O * HID / 4);
  convert_to_bf16<<<1024, 256, 0, stream>>>(wo_f, wo_c, HID * NH * HD / 4);
  convert_to_bf16<<<1, 32, 0, stream>>>(qn_f, qn_c, HD / 4);
  convert_to_bf16<<<1, 32, 0, stream>>>(kn_f, kn_c, HD / 4);

  // K1a: Q slice: qkv[:, :4096] = hidden @ w_qkv[:4096]^T (4096x4096, K=2048)
  // on the R3-proven gemm256: 16x16 = 256 blocks = exactly 1 round.
  gemm256<false, false><<<dim3(NH * HD / 256, NTOK / 256), 512, 0, stream>>>(
      hidden_c, wqkv_c, qkv, qkv, HID, HID, QKV_O, HID);
  // K1b: KV slice: qkv[:, 4096:5120] = hidden @ w_qkv[4096:]^T (4096x1024)
  // on the 128^2 kernel: 8x32 = 256 blocks, 2/CU, 1 round.
  gemm_bt_bf16<false><<<dim3(2 * NKV * HD / 128, NTOK / 128), 256, 0, stream>>>(
      hidden_c, wqkv_c + (size_t)(NH * HD) * HID, qkv + NH * HD, HID, HID, QKV_O, HID);
  // K1c: rope table (hidden_c dead now; table overwrites it)
  rope_tab<<<NTOK, 64, 0, stream>>>(positions, rtab);
  // K2: rmsnorm + rope, in place on q & k head slots (4 heads/block)
  normrope<<<dim3((NH + NKV) / 4, SEQ, BATCH), 256, 0, stream>>>(qkv, rtab, qn_c, kn_c);
  // K2b: V transpose into vt_g
  transpose_v<<<dim3(SEQ / 64, NKV, BATCH), 256, 0, stream>>>(qkv, vt_g);
  // K3: MFMA causal GQA attention (v6)
  flash_mfma<<<dim3(SEQ / 256, NH, BATCH), 512, 0, stream>>>(qkv, vt_g);
  // K4: out = attn @ w_o^T (4096 x 2048, K=4096), split-K=2 -> 256 blocks:
  // z=0 -> p0 (fp32 partial, k 0..2047), z=1 -> out (k 2048..4095)
  gemm256<true, true><<<dim3(HID / 256, NTOK / 256, 2), 512, 0, stream>>>(
      qkv, wo_c, p0, out, QKV_O, NH * HD, HID, NH * HD / 2);
  // K4b: out += p0
  reduce_add<<<2048, 256, 0, stream>>>(out, p0, NTOK * HID / 4);
}